// Round 1
// baseline (964.060 us; speedup 1.0000x reference)
//
#include <hip/hip_runtime.h>

// out[b][pc] = sum_n x[b][n] * kern[n][pc]
//   B=32, N=16384, PC=8192 (=256 patch_vox * 32 nb_patches)
// HBM-bound on the 537 MB kernel tensor (read once). Each thread loads a
// float4 of K and reuses it across all 32 batch rows (128 fp32 accs).

#define B_DIM  32
#define NVOX   16384
#define PC_DIM 8192
#define CHUNK  256      // n-elements per block
#define TPB    256      // threads per block; each owns 4 pc columns
#define XPAD   36       // 32 b-values padded to 36 (16B-aligned rows, breaks bank conflicts)

__global__ __launch_bounds__(TPB, 2)
void lp_gemm_kernel(const float* __restrict__ x,
                    const float* __restrict__ kern,
                    float* __restrict__ out) {
    __shared__ float xs[CHUNK][XPAD];

    const int t  = threadIdx.x;
    const int n0 = blockIdx.y * CHUNK;
    const int c4 = blockIdx.x * TPB + t;   // float4 column index [0, 2048)

    // Stage x[:, n0:n0+CHUNK] into LDS transposed: xs[j][b] = x[b][n0+j].
    // Global reads coalesced over n (lane = j).
#pragma unroll
    for (int b = 0; b < B_DIM; ++b) {
        xs[t][b] = x[b * NVOX + n0 + t];
    }
    __syncthreads();

    float4 acc[B_DIM];
#pragma unroll
    for (int b = 0; b < B_DIM; ++b) acc[b] = make_float4(0.f, 0.f, 0.f, 0.f);

    const float4* __restrict__ k4 = (const float4*)kern;

#pragma unroll 4
    for (int j = 0; j < CHUNK; ++j) {
        // 16B/lane coalesced load of the streamed kernel tensor
        float4 kv = k4[(n0 + j) * (PC_DIM / 4) + c4];
        const float* xrow = &xs[j][0];
#pragma unroll
        for (int b8 = 0; b8 < 8; ++b8) {
            // wave-uniform address -> ds_read_b128 broadcast (conflict-free)
            float4 xv = *(const float4*)(xrow + b8 * 4);
            const int bb = b8 * 4;
            acc[bb+0].x += xv.x * kv.x; acc[bb+0].y += xv.x * kv.y;
            acc[bb+0].z += xv.x * kv.z; acc[bb+0].w += xv.x * kv.w;
            acc[bb+1].x += xv.y * kv.x; acc[bb+1].y += xv.y * kv.y;
            acc[bb+1].z += xv.y * kv.z; acc[bb+1].w += xv.y * kv.w;
            acc[bb+2].x += xv.z * kv.x; acc[bb+2].y += xv.z * kv.y;
            acc[bb+2].z += xv.z * kv.z; acc[bb+2].w += xv.z * kv.w;
            acc[bb+3].x += xv.w * kv.x; acc[bb+3].y += xv.w * kv.y;
            acc[bb+3].z += xv.w * kv.z; acc[bb+3].w += xv.w * kv.w;
        }
    }

    // Combine 64 n-chunk partials per output via fp32 atomics (L2-resident).
    const int pc0 = c4 * 4;
#pragma unroll
    for (int b = 0; b < B_DIM; ++b) {
        float* o = out + b * PC_DIM + pc0;
        atomicAdd(o + 0, acc[b].x);
        atomicAdd(o + 1, acc[b].y);
        atomicAdd(o + 2, acc[b].z);
        atomicAdd(o + 3, acc[b].w);
    }
}

extern "C" void kernel_launch(void* const* d_in, const int* in_sizes, int n_in,
                              void* d_out, int out_size, void* d_ws, size_t ws_size,
                              hipStream_t stream) {
    const float* x    = (const float*)d_in[0];   // (32, 128, 128) = (32, 16384)
    const float* kern = (const float*)d_in[1];   // (16384, 256, 32) = (16384, 8192)
    float* out = (float*)d_out;                  // (32, 16, 16, 32) = (32, 8192)

    // d_out is poisoned to 0xAA before every timed launch; zero it for atomics.
    hipMemsetAsync(out, 0, (size_t)out_size * sizeof(float), stream);

    dim3 grid(PC_DIM / (TPB * 4), NVOX / CHUNK);   // (8, 64) = 512 blocks
    lp_gemm_kernel<<<grid, TPB, 0, stream>>>(x, kern, out);
}

// Round 2
// 698.126 us; speedup vs baseline: 1.3809x; 1.3809x over previous
//
#include <hip/hip_runtime.h>

// out[b][pc] = sum_n x[b][n] * kern[n][pc]
//   B=32, N=16384, PC=8192. HBM-bound on the 537 MB kern stream.
//
// R2 design: thread = 1 pc-column, 32 fp32 accs (one per batch). x is
// pre-transposed to xT[n][b] in d_ws so the inner loop reads it with
// wave-uniform (scalar-path) loads -> no LDS port pressure, no 64-copy
// register-write cost. K split 32 ways (CHUNK=512) -> 1024 blocks = 4
// blocks/CU = 16 waves/CU for latency hiding; low VGPR leaves the
// compiler room to software-pipeline the kv stream loads.

#define B_DIM  32
#define NVOX   16384
#define PC_DIM 8192
#define KSPLIT 32
#define CHUNK  (NVOX / KSPLIT)   // 512
#define TPB    256

// --- transpose x (B, N) -> xt (N, B), fully coalesced via LDS tile ---
__global__ __launch_bounds__(TPB)
void lp_transpose(const float* __restrict__ x, float* __restrict__ xt) {
    __shared__ float s[B_DIM][TPB + 1];
    const int t  = threadIdx.x;
    const int n0 = blockIdx.x * TPB;
#pragma unroll
    for (int b = 0; b < B_DIM; ++b)
        s[b][t] = x[(size_t)b * NVOX + n0 + t];       // coalesced over n
    __syncthreads();
#pragma unroll
    for (int g = 0; g < B_DIM; ++g) {
        const int flat = g * TPB + t;                  // consecutive out addrs
        const int i = flat >> 5;                       // n offset in tile
        const int b = flat & 31;                       // batch
        xt[(size_t)(n0 + i) * B_DIM + b] = s[b][i];    // coalesced write
    }
}

// --- main GEMM: each thread streams one kern column chunk ---
template<bool USE_XT>
__global__ __launch_bounds__(TPB, 4)   // VGPR cap 128; need ~50
void lp_gemm(const float* __restrict__ kern, const float* __restrict__ x,
             const float* __restrict__ xt, float* __restrict__ out) {
    const int c  = blockIdx.x * TPB + threadIdx.x;     // pc column [0,8192)
    const int n0 = blockIdx.y * CHUNK;

    float acc[B_DIM];
#pragma unroll
    for (int b = 0; b < B_DIM; ++b) acc[b] = 0.f;

    const float* kp = kern + (size_t)n0 * PC_DIM + c;

#pragma unroll 4
    for (int j = 0; j < CHUNK; ++j) {
        const float kv = kp[(size_t)j * PC_DIM];       // coalesced HBM stream
        if (USE_XT) {
            // wave-uniform address, read-only, no aliasing stores ->
            // scalar (s_load) path; v_fma with one SGPR operand.
            const float* __restrict__ xr = xt + (size_t)(n0 + j) * B_DIM;
#pragma unroll
            for (int b = 0; b < B_DIM; ++b)
                acc[b] = fmaf(xr[b], kv, acc[b]);
        } else {
            // fallback if ws too small: strided uniform reads of original x
#pragma unroll
            for (int b = 0; b < B_DIM; ++b)
                acc[b] = fmaf(x[(size_t)b * NVOX + n0 + j], kv, acc[b]);
        }
    }

    // 32 n-chunk partials per output; fp32 atomics (8.4M total).
#pragma unroll
    for (int b = 0; b < B_DIM; ++b)
        atomicAdd(&out[(size_t)b * PC_DIM + c], acc[b]);
}

extern "C" void kernel_launch(void* const* d_in, const int* in_sizes, int n_in,
                              void* d_out, int out_size, void* d_ws, size_t ws_size,
                              hipStream_t stream) {
    const float* x    = (const float*)d_in[0];   // (32, 16384)
    const float* kern = (const float*)d_in[1];   // (16384, 8192)
    float* out = (float*)d_out;                  // (32, 8192)

    hipMemsetAsync(out, 0, (size_t)out_size * sizeof(float), stream);

    const size_t xt_bytes = (size_t)NVOX * B_DIM * sizeof(float);  // 2 MB
    dim3 grid(PC_DIM / TPB, KSPLIT);             // (32, 32) = 1024 blocks

    if (ws_size >= xt_bytes) {
        float* xt = (float*)d_ws;
        lp_transpose<<<NVOX / TPB, TPB, 0, stream>>>(x, xt);
        lp_gemm<true><<<grid, TPB, 0, stream>>>(kern, x, xt, out);
    } else {
        lp_gemm<false><<<grid, TPB, 0, stream>>>(kern, x, x, out);
    }
}